// Round 6
// baseline (225.925 us; speedup 1.0000x reference)
//
#include <hip/hip_runtime.h>
#include <hip/hip_bf16.h>

// HET relational attention layer.
//  K1 build_wextT   : W_extT bf16[576][128] = [proj cols 512 | el 32 | er 32]^T
//  K2 gemm_direct   : proj(bf16)[N,512], elr(f32)[N,64] = A(f32->bf16 in-reg) @ W_ext (MFMA)
//                     SWAPPED operands: mfma(w,a) => acc regs walk columns -> packed 8B/16B stores.
//                     grid (NNP/128, 3): 3 col-blocks per block for occupancy.
//  CSR build (bucketed): zero/count/scan/bucket_scatter/exact_place (low write-amp).
//  K_agg            : 1 wave per dst node; fast path deg<=64: exp once per edge -> LDS,
//                     serial column pass unrolled x8; denom folded in.

#define NN 100000
#define NNP 100096            // 782*128
#define NE 1600000
#define NH 4
#define INF_ 128
#define DH 16
#define NCOL 576
#define LEAKY 0.2f
#define NBUCK 391             // ceil(100000/256)
#define BSHIFT 8
#define CHUNK 4096

typedef __hip_bfloat16 bf16;
typedef __attribute__((ext_vector_type(8))) short bf16x8;
typedef __attribute__((ext_vector_type(4))) short bf16x4;
typedef __attribute__((ext_vector_type(4))) float f32x4;

static __device__ __forceinline__ short f2bs(float x) {
    bf16 b = __float2bfloat16(x);
    return *reinterpret_cast<short*>(&b);
}

__global__ void build_wextT(const float* __restrict__ W, const float* __restrict__ al,
                            const float* __restrict__ ar, short* __restrict__ wextT) {
    int idx = blockIdx.x * 256 + threadIdx.x;
    if (idx >= NCOL * INF_) return;
    int c = idx / INF_, i = idx % INF_;
    float v;
    if (c < 512) {
        int r = c >> 6, rem = c & 63, h = rem >> 4, d = rem & 15;
        v = W[((r * NH + h) * INF_ + i) * DH + d];
    } else {
        int rh = c - 512;
        const float* a = al;
        if (rh >= 32) { rh -= 32; a = ar; }
        int r = rh >> 2, h = rh & 3;
        const float* wp = &W[((r * NH + h) * INF_ + i) * DH];
        const float* ap = &a[(r * NH + h) * DH];
        float s = 0.f;
        #pragma unroll
        for (int d = 0; d < DH; ++d) s += wp[d] * ap[d];
        v = s;
    }
    wextT[c * INF_ + i] = f2bs(v);
}

// Block = 4 waves; wave owns 32 rows x 192 cols (3 col-blocks). Grid (NNP/128, 3).
__global__ __launch_bounds__(256) void gemm_direct(
    const float* __restrict__ A, const short* __restrict__ WxT,
    bf16* __restrict__ projb, float* __restrict__ elr) {
    int t = threadIdx.x;
    int wave = t >> 6, lane = t & 63;
    int n0 = blockIdx.x * 128 + wave * 32;
    int g = lane >> 4, r = lane & 15;

    // A fragments: lane holds A[n0 + nt*16 + r][ks*32 + g*8 .. +7] (bf16)
    bf16x8 afr[2][4];
    #pragma unroll
    for (int nt = 0; nt < 2; ++nt) {
        int row = n0 + nt * 16 + r;
        #pragma unroll
        for (int ks = 0; ks < 4; ++ks) {
            int k0 = ks * 32 + g * 8;
            bf16x8 v;
            if (row < NN) {
                float4 f0 = *(const float4*)&A[row * INF_ + k0];
                float4 f1 = *(const float4*)&A[row * INF_ + k0 + 4];
                v[0] = f2bs(f0.x); v[1] = f2bs(f0.y); v[2] = f2bs(f0.z); v[3] = f2bs(f0.w);
                v[4] = f2bs(f1.x); v[5] = f2bs(f1.y); v[6] = f2bs(f1.z); v[7] = f2bs(f1.w);
            } else {
                v = (bf16x8)(short)0;
            }
            afr[nt][ks] = v;
        }
    }

    #pragma unroll
    for (int cbi = 0; cbi < 3; ++cbi) {
        int c0 = (blockIdx.y * 3 + cbi) * 64;
        // acc[nt][ct] = C^T tile: lane(g,r) reg q -> row n = n0+nt*16+r, col c = c0+ct*16+g*4+q
        f32x4 acc[2][4] = {};
        #pragma unroll
        for (int ks = 0; ks < 4; ++ks) {
            int k0 = ks * 32 + g * 8;
            #pragma unroll
            for (int ct = 0; ct < 4; ++ct) {
                bf16x8 b = *(const bf16x8*)&WxT[(c0 + ct * 16 + r) * INF_ + k0];
                acc[0][ct] = __builtin_amdgcn_mfma_f32_16x16x32_bf16(b, afr[0][ks], acc[0][ct], 0, 0, 0);
                acc[1][ct] = __builtin_amdgcn_mfma_f32_16x16x32_bf16(b, afr[1][ks], acc[1][ct], 0, 0, 0);
            }
        }
        #pragma unroll
        for (int nt = 0; nt < 2; ++nt) {
            int n = n0 + nt * 16 + r;
            if (n >= NN) continue;
            if (c0 < 512) {
                #pragma unroll
                for (int ct = 0; ct < 4; ++ct) {
                    bf16x4 p;
                    p[0] = f2bs(acc[nt][ct][0]); p[1] = f2bs(acc[nt][ct][1]);
                    p[2] = f2bs(acc[nt][ct][2]); p[3] = f2bs(acc[nt][ct][3]);
                    *(bf16x4*)&projb[n * 512 + c0 + ct * 16 + g * 4] = p;
                }
            } else {
                #pragma unroll
                for (int ct = 0; ct < 4; ++ct)
                    *(float4*)&elr[n * 64 + ct * 16 + g * 4] = *(float4*)&acc[nt][ct];
            }
        }
    }
}

__global__ void zero_buckets(int* __restrict__ bucketCount) {
    int i = blockIdx.x * 256 + threadIdx.x;
    if (i < NBUCK) bucketCount[i] = 0;
}

__global__ __launch_bounds__(256) void bucket_count(const int* __restrict__ dst,
                                                    int* __restrict__ bucketCount) {
    __shared__ int hist[NBUCK];
    int t = threadIdx.x;
    for (int i = t; i < NBUCK; i += 256) hist[i] = 0;
    __syncthreads();
    int base = blockIdx.x * CHUNK;
    #pragma unroll
    for (int j = 0; j < CHUNK / 256; ++j) {
        int e = base + j * 256 + t;
        if (e < NE) atomicAdd(&hist[dst[e] >> BSHIFT], 1);
    }
    __syncthreads();
    for (int i = t; i < NBUCK; i += 256) {
        int v = hist[i];
        if (v) atomicAdd(&bucketCount[i], v);
    }
}

__global__ __launch_bounds__(256) void scan_buckets(const int* __restrict__ bucketCount,
                                                    int* __restrict__ bucketOff,
                                                    int* __restrict__ gCursor) {
    __shared__ int tsum[256];
    int t = threadIdx.x;
    int i0 = 2 * t, i1 = 2 * t + 1;
    int a = (i0 < NBUCK) ? bucketCount[i0] : 0;
    int b = (i1 < NBUCK) ? bucketCount[i1] : 0;
    int own = a + b;
    tsum[t] = own;
    __syncthreads();
    for (int st = 1; st < 256; st <<= 1) {
        int y = (t >= st) ? tsum[t - st] : 0;
        __syncthreads();
        tsum[t] += y;
        __syncthreads();
    }
    int excl = tsum[t] - own;
    if (i0 <= NBUCK) { bucketOff[i0] = excl; if (i0 < NBUCK) gCursor[i0] = excl; }
    if (i1 <= NBUCK) { bucketOff[i1] = excl + a; if (i1 < NBUCK) gCursor[i1] = excl + a; }
}

// rec32 = (dst&255)<<20 | (src*8+rel)
__global__ __launch_bounds__(256) void bucket_scatter(
    const int* __restrict__ src, const int* __restrict__ dst, const int* __restrict__ rel,
    int* __restrict__ gCursor, int* __restrict__ pairbuf) {
    __shared__ int hist[NBUCK];
    int t = threadIdx.x;
    for (int i = t; i < NBUCK; i += 256) hist[i] = 0;
    __syncthreads();
    int base = blockIdx.x * CHUNK;
    #pragma unroll
    for (int j = 0; j < CHUNK / 256; ++j) {
        int e = base + j * 256 + t;
        if (e < NE) atomicAdd(&hist[dst[e] >> BSHIFT], 1);
    }
    __syncthreads();
    for (int i = t; i < NBUCK; i += 256) {
        int v = hist[i];
        hist[i] = v ? atomicAdd(&gCursor[i], v) : 0;
    }
    __syncthreads();
    #pragma unroll
    for (int j = 0; j < CHUNK / 256; ++j) {
        int e = base + j * 256 + t;
        if (e < NE) {
            int d = dst[e];
            int b = d >> BSHIFT;
            int rec = ((d & 255) << 20) | (src[e] * 8 + rel[e]);
            int pos = atomicAdd(&hist[b], 1);
            pairbuf[pos] = rec;
        }
    }
}

__global__ __launch_bounds__(256) void exact_place(
    const int* __restrict__ bucketOff, const int* __restrict__ pairbuf,
    int* __restrict__ offsets, int* __restrict__ rec_srcrel) {
    __shared__ int hist[256];
    __shared__ int tsum[256];
    int b = blockIdx.x, t = threadIdx.x;
    int start = bucketOff[b], cnt = bucketOff[b + 1] - start;
    hist[t] = 0;
    __syncthreads();
    for (int i = t; i < cnt; i += 256) atomicAdd(&hist[pairbuf[start + i] >> 20], 1);
    __syncthreads();
    int own = hist[t];
    tsum[t] = own;
    __syncthreads();
    for (int st = 1; st < 256; st <<= 1) {
        int y = (t >= st) ? tsum[t - st] : 0;
        __syncthreads();
        tsum[t] += y;
        __syncthreads();
    }
    int excl = start + tsum[t] - own;
    int node = b * 256 + t;
    if (node <= NN) offsets[node] = excl;
    __syncthreads();
    hist[t] = excl;
    __syncthreads();
    for (int i = t; i < cnt; i += 256) {
        int rec = pairbuf[start + i];
        int pos = atomicAdd(&hist[rec >> 20], 1);
        rec_srcrel[pos] = rec & 0xFFFFF;
    }
}

__global__ __launch_bounds__(256) void agg(
    const int* __restrict__ offsets, const int* __restrict__ rec_srcrel,
    const float* __restrict__ elr, const bf16* __restrict__ projb,
    const float* __restrict__ bias, float* __restrict__ out) {
    __shared__ float s_alpha[4][64][4];
    __shared__ int   s_rec[4][64];
    __shared__ float s_er[4][32];
    int wv = threadIdx.x >> 6, lane = threadIdx.x & 63;
    int d = blockIdx.x * 4 + wv;
    if (d >= NN) return;
    int off = offsets[d], end = offsets[d + 1];
    int deg = end - off;
    int c = lane, h = c >> 4;

    if (lane < 32) s_er[wv][lane] = elr[d * 64 + 32 + lane];
    __builtin_amdgcn_wave_barrier();
    asm volatile("s_waitcnt lgkmcnt(0)" ::: "memory");

    float res;
    if (deg == 0) {
        res = 0.f;
    } else if (deg <= 64) {
        int i = off + lane;
        float e0 = 0.f, e1 = 0.f, e2 = 0.f, e3 = 0.f;
        int rec = 0;
        if (i < end) {
            rec = rec_srcrel[i];
            int s = rec >> 3, r = rec & 7;
            float4 el4 = *(const float4*)&elr[s * 64 + r * 4];
            float x;
            x = el4.x + s_er[wv][r * 4 + 0]; x = x > 0.f ? x : LEAKY * x; e0 = __expf(x);
            x = el4.y + s_er[wv][r * 4 + 1]; x = x > 0.f ? x : LEAKY * x; e1 = __expf(x);
            x = el4.z + s_er[wv][r * 4 + 2]; x = x > 0.f ? x : LEAKY * x; e2 = __expf(x);
            x = el4.w + s_er[wv][r * 4 + 3]; x = x > 0.f ? x : LEAKY * x; e3 = __expf(x);
        }
        s_rec[wv][lane] = rec;
        *(float4*)&s_alpha[wv][lane][0] = make_float4(e0, e1, e2, e3);
        __builtin_amdgcn_wave_barrier();
        asm volatile("s_waitcnt lgkmcnt(0)" ::: "memory");

        float acc = 0.f, dsum = 0.f;
        int j = 0;
        for (; j + 8 <= deg; j += 8) {
            float vv[8], aa[8];
            #pragma unroll
            for (int u = 0; u < 8; ++u) {
                int sr = s_rec[wv][j + u];
                aa[u] = s_alpha[wv][j + u][h];
                vv[u] = __bfloat162float(projb[sr * 64 + c]);
            }
            #pragma unroll
            for (int u = 0; u < 8; ++u) {
                dsum += aa[u];
                acc = fmaf(aa[u], vv[u], acc);
            }
        }
        for (; j < deg; ++j) {
            int sr = s_rec[wv][j];
            float a = s_alpha[wv][j][h];
            float v = __bfloat162float(projb[sr * 64 + c]);
            dsum += a;
            acc = fmaf(a, v, acc);
        }
        res = acc / dsum;
    } else {
        float dsum0 = 0.f, dsum1 = 0.f, dsum2 = 0.f, dsum3 = 0.f;
        for (int i = off + lane; i < end; i += 64) {
            int sr = rec_srcrel[i];
            int s = sr >> 3, r = sr & 7;
            float4 el4 = *(const float4*)&elr[s * 64 + r * 4];
            float x;
            x = el4.x + s_er[wv][r * 4 + 0]; x = x > 0.f ? x : LEAKY * x; dsum0 += __expf(x);
            x = el4.y + s_er[wv][r * 4 + 1]; x = x > 0.f ? x : LEAKY * x; dsum1 += __expf(x);
            x = el4.z + s_er[wv][r * 4 + 2]; x = x > 0.f ? x : LEAKY * x; dsum2 += __expf(x);
            x = el4.w + s_er[wv][r * 4 + 3]; x = x > 0.f ? x : LEAKY * x; dsum3 += __expf(x);
        }
        #pragma unroll
        for (int m = 32; m; m >>= 1) {
            dsum0 += __shfl_xor(dsum0, m, 64);
            dsum1 += __shfl_xor(dsum1, m, 64);
            dsum2 += __shfl_xor(dsum2, m, 64);
            dsum3 += __shfl_xor(dsum3, m, 64);
        }
        float dh = (h == 0) ? dsum0 : (h == 1) ? dsum1 : (h == 2) ? dsum2 : dsum3;
        float rd = 1.0f / dh;
        float acc = 0.f;
        for (int i = off; i < end; ++i) {
            int sr = rec_srcrel[i];
            int s = sr >> 3, r = sr & 7;
            float x = elr[s * 64 + r * 4 + h] + s_er[wv][r * 4 + h];
            x = x > 0.f ? x : LEAKY * x;
            acc = fmaf(__expf(x) * rd, __bfloat162float(projb[sr * 64 + c]), acc);
        }
        res = acc;
    }
    out[d * 64 + c] = res + bias[c];
}

extern "C" void kernel_launch(void* const* d_in, const int* in_sizes, int n_in,
                              void* d_out, int out_size, void* d_ws, size_t ws_size,
                              hipStream_t stream) {
    const float* inputs = (const float*)d_in[0];
    const float* convw  = (const float*)d_in[1];
    const float* attn_l = (const float*)d_in[2];
    const float* attn_r = (const float*)d_in[3];
    const float* h_bias = (const float*)d_in[4];
    const int*   src    = (const int*)d_in[5];
    const int*   dst    = (const int*)d_in[6];
    const int*   rel    = (const int*)d_in[7];
    float* out = (float*)d_out;

    char* ws = (char*)d_ws;
    size_t o = 0;
    bf16* projb = (bf16*)(ws + o);  o += 102400000ull;
    float* elr  = (float*)(ws + o); o += 25600000ull;
    short* wextT = (short*)(ws + o); o += 147456;
    int* offsets     = (int*)(ws + o); o += 400128;
    int* bucketCount = (int*)(ws + o); o += 1600;
    int* bucketOff   = (int*)(ws + o); o += 1600;
    int* gCursor     = (int*)(ws + o); o += 1600;
    int* pairbuf     = (int*)(ws + o); o += 6400000ull;
    int* rec_srcrel  = (int*)(ws + o); o += 6400000ull;

    hipLaunchKernelGGL(build_wextT, dim3(288), dim3(256), 0, stream, convw, attn_l, attn_r, wextT);
    hipLaunchKernelGGL(gemm_direct, dim3(NNP / 128, 3), dim3(256), 0, stream, inputs, wextT, projb, elr);
    hipLaunchKernelGGL(zero_buckets, dim3(2), dim3(256), 0, stream, bucketCount);
    hipLaunchKernelGGL(bucket_count, dim3(NBUCK), dim3(256), 0, stream, dst, bucketCount);
    hipLaunchKernelGGL(scan_buckets, dim3(1), dim3(256), 0, stream, bucketCount, bucketOff, gCursor);
    hipLaunchKernelGGL(bucket_scatter, dim3(NBUCK), dim3(256), 0, stream, src, dst, rel, gCursor, pairbuf);
    hipLaunchKernelGGL(exact_place, dim3(NBUCK), dim3(256), 0, stream, bucketOff, pairbuf, offsets, rec_srcrel);
    hipLaunchKernelGGL(agg, dim3(25000), dim3(256), 0, stream, offsets, rec_srcrel, elr, projb, h_bias, out);
}

// Round 8
// 183.112 us; speedup vs baseline: 1.2338x; 1.2338x over previous
//
#include <hip/hip_runtime.h>
#include <hip/hip_bf16.h>

// HET relational attention layer.
//  K1 build_wextT : W_ext in FRAGMENT-MAJOR layout: idx = (((cb*4+ks)*4+ct)*64+lane)*8+e
//                   -> every gemm B-frag load is wave-contiguous 1KB.
//  K2 gemm_direct : per block (4 waves, 128 rows): stage A f32->bf16 into XOR-swizzled LDS
//                   (coalesced reads), frag ds_reads once, then 9 col-blocks of MFMA.
//                   C goes acc -> swizzled per-wave LDS slice -> coalesced 1KB stores.
//                   projR layout [rel][node][64] so each cb's stores are contiguous.
//  CSR build      : bucketed (zero/count/scan/bucket_scatter/exact_place).
//  K_agg          : 1 wave per dst node; fast path deg<=64; unrolled x8 gather.
// R7 fix: elr store row stride was q*1024 floats (q*16 rows) but rr advances q*4 rows
//         -> must be q*256. Caused races + wrong scores (absmax 4.06). Single-line fix.

#define NN 100000
#define NNP 100096            // 782*128
#define NE 1600000
#define NH 4
#define INF_ 128
#define DH 16
#define NCOL 576
#define LEAKY 0.2f
#define NBUCK 391
#define BSHIFT 8
#define CHUNK 4096

typedef __hip_bfloat16 bf16;
typedef __attribute__((ext_vector_type(8))) short bf16x8;
typedef __attribute__((ext_vector_type(4))) short bf16x4;
typedef __attribute__((ext_vector_type(4))) float f32x4;

static __device__ __forceinline__ short f2bs(float x) {
    bf16 b = __float2bfloat16(x);
    return *reinterpret_cast<short*>(&b);
}

// Fragment-major W: for (cb,ks,ct,lane=g*16+r,e): col = cb*64+ct*16+r, k = ks*32+g*8+e.
__global__ void build_wextT(const float* __restrict__ W, const float* __restrict__ al,
                            const float* __restrict__ ar, short* __restrict__ wxt2) {
    int idx = blockIdx.x * 256 + threadIdx.x;
    if (idx >= NCOL * INF_) return;
    int e = idx & 7, lane = (idx >> 3) & 63, ct = (idx >> 9) & 3, ks = (idx >> 11) & 3, cb = idx >> 13;
    int g = lane >> 4, r = lane & 15;
    int c = cb * 64 + ct * 16 + r;
    int k = ks * 32 + g * 8 + e;
    float v;
    if (c < 512) {
        int rr = c >> 6, rem = c & 63, h = rem >> 4, d = rem & 15;
        v = W[((rr * NH + h) * INF_ + k) * DH + d];
    } else {
        int rh = c - 512;
        const float* a = al;
        if (rh >= 32) { rh -= 32; a = ar; }
        int rr = rh >> 2, h = rh & 3;
        const float* wp = &W[((rr * NH + h) * INF_ + k) * DH];
        const float* ap = &a[(rr * NH + h) * DH];
        float s = 0.f;
        #pragma unroll
        for (int d = 0; d < DH; ++d) s += wp[d] * ap[d];
        v = s;
    }
    wxt2[idx] = f2bs(v);
}

// Block = 4 waves, 128 rows, all 576 cols. All VMEM contiguous.
__global__ __launch_bounds__(256) void gemm_direct(
    const float* __restrict__ A, const short* __restrict__ WxT2,
    bf16* __restrict__ projR, float* __restrict__ elr) {
    __shared__ short As[16384];          // 32 KB: A-tile (swizzled), later C-stage slices
    int t = threadIdx.x;
    int wv = t >> 6, lane = t & 63;
    int n0 = blockIdx.x * 128;
    int g = lane >> 4, r = lane & 15;

    // Phase 1: stage A (coalesced f32 reads -> bf16 -> swizzled LDS).
    // chunk i = 8 floats: row = i>>4, c8 = i&15; phys granule = row*16 + (c8 ^ (row&7)).
    #pragma unroll
    for (int j = 0; j < 8; ++j) {
        int i = j * 256 + t;
        int row = i >> 4, c8 = i & 15;
        int gr = n0 + row;
        bf16x8 v;
        if (gr < NN) {
            float4 f0 = *(const float4*)&A[gr * INF_ + c8 * 8];
            float4 f1 = *(const float4*)&A[gr * INF_ + c8 * 8 + 4];
            v[0] = f2bs(f0.x); v[1] = f2bs(f0.y); v[2] = f2bs(f0.z); v[3] = f2bs(f0.w);
            v[4] = f2bs(f1.x); v[5] = f2bs(f1.y); v[6] = f2bs(f1.z); v[7] = f2bs(f1.w);
        } else {
            v = (bf16x8)(short)0;
        }
        *(bf16x8*)&As[(row * 16 + (c8 ^ (row & 7))) * 8] = v;
    }
    __syncthreads();

    // Phase 2: A fragments (one-time). row = wv*32+nt*16+r; granule (ks*4+g)^(r&7).
    bf16x8 afr[2][4];
    #pragma unroll
    for (int nt = 0; nt < 2; ++nt) {
        int row = wv * 32 + nt * 16 + r;
        #pragma unroll
        for (int ks = 0; ks < 4; ++ks)
            afr[nt][ks] = *(const bf16x8*)&As[(row * 16 + ((ks * 4 + g) ^ (r & 7))) * 8];
    }
    __syncthreads();                      // A-tile dead; reuse as C-stage
    short* Csh = &As[wv * 4096];          // per-wave 8 KB slice
    float* Csf = (float*)Csh;
    int n0w = n0 + wv * 32;

    for (int cb = 0; cb < 9; ++cb) {
        f32x4 acc[2][4] = {};
        #pragma unroll
        for (int ks = 0; ks < 4; ++ks) {
            #pragma unroll
            for (int ct = 0; ct < 4; ++ct) {
                bf16x8 b = *(const bf16x8*)&WxT2[(((cb * 4 + ks) * 4 + ct) * 64 + lane) * 8];
                acc[0][ct] = __builtin_amdgcn_mfma_f32_16x16x32_bf16(b, afr[0][ks], acc[0][ct], 0, 0, 0);
                acc[1][ct] = __builtin_amdgcn_mfma_f32_16x16x32_bf16(b, afr[1][ks], acc[1][ct], 0, 0, 0);
            }
        }
        // lane(g,r), reg q: row = n0w + nt*16 + r, col = cb*64 + ct*16 + g*4 + q.
        if (cb < 8) {
            // C-stage bf16 [32][64]: 8B granule g8 = ct*4+g, phys = g8 ^ ((rr&7)<<1).
            #pragma unroll
            for (int nt = 0; nt < 2; ++nt) {
                int rr = nt * 16 + r;
                #pragma unroll
                for (int ct = 0; ct < 4; ++ct) {
                    bf16x4 p;
                    p[0] = f2bs(acc[nt][ct][0]); p[1] = f2bs(acc[nt][ct][1]);
                    p[2] = f2bs(acc[nt][ct][2]); p[3] = f2bs(acc[nt][ct][3]);
                    *(bf16x4*)&Csh[rr * 64 + (((ct * 4 + g) ^ ((rr & 7) << 1)) << 2)] = p;
                }
            }
            __builtin_amdgcn_wave_barrier();
            // coalesced: 16B block b16 at row rr -> phys b16 ^ (rr&7); 4x 1KB stores.
            size_t base = ((size_t)cb * NN + n0w) * 64;
            #pragma unroll
            for (int q = 0; q < 4; ++q) {
                int rr = (lane >> 3) + q * 8;
                if (n0w + rr < NN) {
                    bf16x8 vv = *(const bf16x8*)&Csh[rr * 64 + (((lane & 7) ^ (rr & 7)) << 3)];
                    *(bf16x8*)&((short*)projR)[base + q * 512 + lane * 8] = vv;
                }
            }
            __builtin_amdgcn_wave_barrier();
        } else {
            // C-stage f32 [32][64]: 16B granule g16 = ct*4+g, phys = g16 ^ ((rr&7)<<1).
            #pragma unroll
            for (int nt = 0; nt < 2; ++nt) {
                int rr = nt * 16 + r;
                #pragma unroll
                for (int ct = 0; ct < 4; ++ct)
                    *(f32x4*)&Csf[rr * 64 + (((ct * 4 + g) ^ ((rr & 7) << 1)) << 2)] = acc[nt][ct];
            }
            __builtin_amdgcn_wave_barrier();
            // row stride: q advances 4 rows = 4*64 = 256 floats (R7 fix: was q*1024).
            #pragma unroll
            for (int q = 0; q < 8; ++q) {
                int rr = (lane >> 4) + q * 4;
                if (n0w + rr < NN) {
                    f32x4 vv = *(const f32x4*)&Csf[rr * 64 + (((lane & 15) ^ ((rr & 7) << 1)) << 2)];
                    *(f32x4*)&elr[(size_t)n0w * 64 + q * 256 + lane * 4] = vv;
                }
            }
        }
    }
}

__global__ void zero_buckets(int* __restrict__ bucketCount) {
    int i = blockIdx.x * 256 + threadIdx.x;
    if (i < NBUCK) bucketCount[i] = 0;
}

__global__ __launch_bounds__(256) void bucket_count(const int* __restrict__ dst,
                                                    int* __restrict__ bucketCount) {
    __shared__ int hist[NBUCK];
    int t = threadIdx.x;
    for (int i = t; i < NBUCK; i += 256) hist[i] = 0;
    __syncthreads();
    int base = blockIdx.x * CHUNK;
    #pragma unroll
    for (int j = 0; j < CHUNK / 256; ++j) {
        int e = base + j * 256 + t;
        if (e < NE) atomicAdd(&hist[dst[e] >> BSHIFT], 1);
    }
    __syncthreads();
    for (int i = t; i < NBUCK; i += 256) {
        int v = hist[i];
        if (v) atomicAdd(&bucketCount[i], v);
    }
}

__global__ __launch_bounds__(256) void scan_buckets(const int* __restrict__ bucketCount,
                                                    int* __restrict__ bucketOff,
                                                    int* __restrict__ gCursor) {
    __shared__ int tsum[256];
    int t = threadIdx.x;
    int i0 = 2 * t, i1 = 2 * t + 1;
    int a = (i0 < NBUCK) ? bucketCount[i0] : 0;
    int b = (i1 < NBUCK) ? bucketCount[i1] : 0;
    int own = a + b;
    tsum[t] = own;
    __syncthreads();
    for (int st = 1; st < 256; st <<= 1) {
        int y = (t >= st) ? tsum[t - st] : 0;
        __syncthreads();
        tsum[t] += y;
        __syncthreads();
    }
    int excl = tsum[t] - own;
    if (i0 <= NBUCK) { bucketOff[i0] = excl; if (i0 < NBUCK) gCursor[i0] = excl; }
    if (i1 <= NBUCK) { bucketOff[i1] = excl + a; if (i1 < NBUCK) gCursor[i1] = excl + a; }
}

// rec32 = (dst&255)<<20 | (src*8+rel)
__global__ __launch_bounds__(256) void bucket_scatter(
    const int* __restrict__ src, const int* __restrict__ dst, const int* __restrict__ rel,
    int* __restrict__ gCursor, int* __restrict__ pairbuf) {
    __shared__ int hist[NBUCK];
    int t = threadIdx.x;
    for (int i = t; i < NBUCK; i += 256) hist[i] = 0;
    __syncthreads();
    int base = blockIdx.x * CHUNK;
    #pragma unroll
    for (int j = 0; j < CHUNK / 256; ++j) {
        int e = base + j * 256 + t;
        if (e < NE) atomicAdd(&hist[dst[e] >> BSHIFT], 1);
    }
    __syncthreads();
    for (int i = t; i < NBUCK; i += 256) {
        int v = hist[i];
        hist[i] = v ? atomicAdd(&gCursor[i], v) : 0;
    }
    __syncthreads();
    #pragma unroll
    for (int j = 0; j < CHUNK / 256; ++j) {
        int e = base + j * 256 + t;
        if (e < NE) {
            int d = dst[e];
            int b = d >> BSHIFT;
            int rec = ((d & 255) << 20) | (src[e] * 8 + rel[e]);
            int pos = atomicAdd(&hist[b], 1);
            pairbuf[pos] = rec;
        }
    }
}

__global__ __launch_bounds__(256) void exact_place(
    const int* __restrict__ bucketOff, const int* __restrict__ pairbuf,
    int* __restrict__ offsets, int* __restrict__ rec_srcrel) {
    __shared__ int hist[256];
    __shared__ int tsum[256];
    int b = blockIdx.x, t = threadIdx.x;
    int start = bucketOff[b], cnt = bucketOff[b + 1] - start;
    hist[t] = 0;
    __syncthreads();
    for (int i = t; i < cnt; i += 256) atomicAdd(&hist[pairbuf[start + i] >> 20], 1);
    __syncthreads();
    int own = hist[t];
    tsum[t] = own;
    __syncthreads();
    for (int st = 1; st < 256; st <<= 1) {
        int y = (t >= st) ? tsum[t - st] : 0;
        __syncthreads();
        tsum[t] += y;
        __syncthreads();
    }
    int excl = start + tsum[t] - own;
    int node = b * 256 + t;
    if (node <= NN) offsets[node] = excl;
    __syncthreads();
    hist[t] = excl;
    __syncthreads();
    for (int i = t; i < cnt; i += 256) {
        int rec = pairbuf[start + i];
        int pos = atomicAdd(&hist[rec >> 20], 1);
        rec_srcrel[pos] = rec & 0xFFFFF;
    }
}

__global__ __launch_bounds__(256) void agg(
    const int* __restrict__ offsets, const int* __restrict__ rec_srcrel,
    const float* __restrict__ elr, const bf16* __restrict__ projR,
    const float* __restrict__ bias, float* __restrict__ out) {
    __shared__ float s_alpha[4][64][4];
    __shared__ int   s_rec[4][64];
    __shared__ float s_er[4][32];
    int wv = threadIdx.x >> 6, lane = threadIdx.x & 63;
    int d = blockIdx.x * 4 + wv;
    if (d >= NN) return;
    int off = offsets[d], end = offsets[d + 1];
    int deg = end - off;
    int c = lane, h = c >> 4;

    if (lane < 32) s_er[wv][lane] = elr[d * 64 + 32 + lane];
    __builtin_amdgcn_wave_barrier();
    asm volatile("s_waitcnt lgkmcnt(0)" ::: "memory");

    float res;
    if (deg == 0) {
        res = 0.f;
    } else if (deg <= 64) {
        int i = off + lane;
        float e0 = 0.f, e1 = 0.f, e2 = 0.f, e3 = 0.f;
        int rec = 0;
        if (i < end) {
            rec = rec_srcrel[i];
            int s = rec >> 3, r = rec & 7;
            float4 el4 = *(const float4*)&elr[s * 64 + r * 4];
            float x;
            x = el4.x + s_er[wv][r * 4 + 0]; x = x > 0.f ? x : LEAKY * x; e0 = __expf(x);
            x = el4.y + s_er[wv][r * 4 + 1]; x = x > 0.f ? x : LEAKY * x; e1 = __expf(x);
            x = el4.z + s_er[wv][r * 4 + 2]; x = x > 0.f ? x : LEAKY * x; e2 = __expf(x);
            x = el4.w + s_er[wv][r * 4 + 3]; x = x > 0.f ? x : LEAKY * x; e3 = __expf(x);
        }
        s_rec[wv][lane] = rec;
        *(float4*)&s_alpha[wv][lane][0] = make_float4(e0, e1, e2, e3);
        __builtin_amdgcn_wave_barrier();
        asm volatile("s_waitcnt lgkmcnt(0)" ::: "memory");

        float acc = 0.f, dsum = 0.f;
        int j = 0;
        for (; j + 8 <= deg; j += 8) {
            float vv[8], aa[8];
            #pragma unroll
            for (int u = 0; u < 8; ++u) {
                int sr = s_rec[wv][j + u];
                aa[u] = s_alpha[wv][j + u][h];
                vv[u] = __bfloat162float(projR[(sr & 7) * (NN * 64) + (sr >> 3) * 64 + c]);
            }
            #pragma unroll
            for (int u = 0; u < 8; ++u) {
                dsum += aa[u];
                acc = fmaf(aa[u], vv[u], acc);
            }
        }
        for (; j < deg; ++j) {
            int sr = s_rec[wv][j];
            float a = s_alpha[wv][j][h];
            float v = __bfloat162float(projR[(sr & 7) * (NN * 64) + (sr >> 3) * 64 + c]);
            dsum += a;
            acc = fmaf(a, v, acc);
        }
        res = acc / dsum;
    } else {
        float dsum0 = 0.f, dsum1 = 0.f, dsum2 = 0.f, dsum3 = 0.f;
        for (int i = off + lane; i < end; i += 64) {
            int sr = rec_srcrel[i];
            int s = sr >> 3, r = sr & 7;
            float4 el4 = *(const float4*)&elr[s * 64 + r * 4];
            float x;
            x = el4.x + s_er[wv][r * 4 + 0]; x = x > 0.f ? x : LEAKY * x; dsum0 += __expf(x);
            x = el4.y + s_er[wv][r * 4 + 1]; x = x > 0.f ? x : LEAKY * x; dsum1 += __expf(x);
            x = el4.z + s_er[wv][r * 4 + 2]; x = x > 0.f ? x : LEAKY * x; dsum2 += __expf(x);
            x = el4.w + s_er[wv][r * 4 + 3]; x = x > 0.f ? x : LEAKY * x; dsum3 += __expf(x);
        }
        #pragma unroll
        for (int m = 32; m; m >>= 1) {
            dsum0 += __shfl_xor(dsum0, m, 64);
            dsum1 += __shfl_xor(dsum1, m, 64);
            dsum2 += __shfl_xor(dsum2, m, 64);
            dsum3 += __shfl_xor(dsum3, m, 64);
        }
        float dh = (h == 0) ? dsum0 : (h == 1) ? dsum1 : (h == 2) ? dsum2 : dsum3;
        float rd = 1.0f / dh;
        float acc = 0.f;
        for (int i = off; i < end; ++i) {
            int sr = rec_srcrel[i];
            int s = sr >> 3, r = sr & 7;
            float x = elr[s * 64 + r * 4 + h] + s_er[wv][r * 4 + h];
            x = x > 0.f ? x : LEAKY * x;
            acc = fmaf(__expf(x) * rd, __bfloat162float(projR[r * (NN * 64) + s * 64 + c]), acc);
        }
        res = acc;
    }
    out[d * 64 + c] = res + bias[c];
}

extern "C" void kernel_launch(void* const* d_in, const int* in_sizes, int n_in,
                              void* d_out, int out_size, void* d_ws, size_t ws_size,
                              hipStream_t stream) {
    const float* inputs = (const float*)d_in[0];
    const float* convw  = (const float*)d_in[1];
    const float* attn_l = (const float*)d_in[2];
    const float* attn_r = (const float*)d_in[3];
    const float* h_bias = (const float*)d_in[4];
    const int*   src    = (const int*)d_in[5];
    const int*   dst    = (const int*)d_in[6];
    const int*   rel    = (const int*)d_in[7];
    float* out = (float*)d_out;

    char* ws = (char*)d_ws;
    size_t o = 0;
    bf16* projR = (bf16*)(ws + o);  o += 102400000ull;   // [8][NN][64]
    float* elr  = (float*)(ws + o); o += 25600000ull;
    short* wxt2 = (short*)(ws + o); o += 147456;
    int* offsets     = (int*)(ws + o); o += 400128;
    int* bucketCount = (int*)(ws + o); o += 1600;
    int* bucketOff   = (int*)(ws + o); o += 1600;
    int* gCursor     = (int*)(ws + o); o += 1600;
    int* pairbuf     = (int*)(ws + o); o += 6400000ull;
    int* rec_srcrel  = (int*)(ws + o); o += 6400000ull;

    hipLaunchKernelGGL(build_wextT, dim3(288), dim3(256), 0, stream, convw, attn_l, attn_r, wxt2);
    hipLaunchKernelGGL(gemm_direct, dim3(NNP / 128), dim3(256), 0, stream, inputs, wxt2, projR, elr);
    hipLaunchKernelGGL(zero_buckets, dim3(2), dim3(256), 0, stream, bucketCount);
    hipLaunchKernelGGL(bucket_count, dim3(NBUCK), dim3(256), 0, stream, dst, bucketCount);
    hipLaunchKernelGGL(scan_buckets, dim3(1), dim3(256), 0, stream, bucketCount, bucketOff, gCursor);
    hipLaunchKernelGGL(bucket_scatter, dim3(NBUCK), dim3(256), 0, stream, src, dst, rel, gCursor, pairbuf);
    hipLaunchKernelGGL(exact_place, dim3(NBUCK), dim3(256), 0, stream, bucketOff, pairbuf, offsets, rec_srcrel);
    hipLaunchKernelGGL(agg, dim3(25000), dim3(256), 0, stream, offsets, rec_srcrel, elr, projR, h_bias, out);
}